// Round 2
// baseline (5206.506 us; speedup 1.0000x reference)
//
#include <hip/hip_runtime.h>
#include <math.h>

#define NQ        14
#define DIM       16384          // 2^14
#define NLAYERS   5
#define NTHREADS  1024

struct c32 { float x, y; };

__device__ __forceinline__ c32 cmul(c32 a, c32 b) {
    return { a.x * b.x - a.y * b.y, a.x * b.y + a.y * b.x };
}

// LDS amp-index swizzle (amp = float2 = 8B). XORs byte bits 10:9 -> 6:5 and
// 8:7 -> 4:3 so that every pass's quarter-wave access pattern hits 16
// distinct b64 bank slots. Bijective (source bits >= 4 unchanged).
__device__ __forceinline__ int swz(int i) {
    return i ^ (((i >> 6) & 3) << 2) ^ ((i >> 4) & 3);
}

// Apply gate {g0,g1;g2,g3} to register amps on local bit K of a[16].
#define APPLYK(K, GP) { \
    const c32 g0 = (GP)[0], g1 = (GP)[1], g2 = (GP)[2], g3 = (GP)[3]; \
    _Pragma("unroll") \
    for (int m = 0; m < 8; ++m) { \
        const int r0 = ((m >> (K)) << ((K) + 1)) | (m & ((1 << (K)) - 1)); \
        const int r1 = r0 | (1 << (K)); \
        const float2 A0 = a[r0], A1 = a[r1]; \
        float2 B0, B1; \
        B0.x = g0.x*A0.x - g0.y*A0.y + g1.x*A1.x - g1.y*A1.y; \
        B0.y = g0.x*A0.y + g0.y*A0.x + g1.x*A1.y + g1.y*A1.x; \
        B1.x = g2.x*A0.x - g2.y*A0.y + g3.x*A1.x - g3.y*A1.y; \
        B1.y = g2.x*A0.y + g2.y*A0.x + g3.x*A1.y + g3.y*A1.x; \
        a[r0] = B0; a[r1] = B1; \
    } }

__global__ __launch_bounds__(NTHREADS, 4) void pqc_kernel(
    const float* __restrict__ x,      // (B, 14)
    const float* __restrict__ theta,  // (252,)
    const float* __restrict__ lam,    // (70,)
    const float* __restrict__ w,      // (1, 2)
    float* __restrict__ out)          // (B, 2)
{
    __shared__ float2 st[DIM];                // 128 KiB state (swizzled layout)
    __shared__ c32 U[NLAYERS + 1][NQ][4];     // fused RZ*RY*RX
    __shared__ c32 W[NLAYERS][NQ][4];         // U[l+1] * RX(x*lam)
    __shared__ float wsum[NTHREADS / 64];

    const int t = threadIdx.x;
    const int b = blockIdx.x;

    // ---- Build 84 variational gates (theta: 42*l + 3*q + c) ----
    if (t < (NLAYERS + 1) * NQ) {
        const int l = t / NQ, q = t % NQ;
        const float a0 = theta[3 * t + 0];
        const float a1 = theta[3 * t + 1];
        const float a2 = theta[3 * t + 2];
        const float cx = cosf(0.5f * a0), sx = sinf(0.5f * a0);
        const float cy = cosf(0.5f * a1), sy = sinf(0.5f * a1);
        const float cz = cosf(0.5f * a2), sz = sinf(0.5f * a2);
        const c32 m00 = {  cy * cx,  sy * sx };
        const c32 m01 = { -sy * cx, -cy * sx };
        const c32 m10 = {  sy * cx, -cy * sx };
        const c32 m11 = {  cy * cx, -sy * sx };
        const c32 ezm = { cz, -sz }, ezp = { cz, sz };
        U[l][q][0] = cmul(ezm, m00);
        U[l][q][1] = cmul(ezm, m01);
        U[l][q][2] = cmul(ezp, m10);
        U[l][q][3] = cmul(ezp, m11);
    }
    __syncthreads();

    // ---- Fuse encoding RX into following variational gate ----
    if (t < NLAYERS * NQ) {
        const int l = t / NQ, q = t % NQ;
        const float ang = x[b * NQ + q] * lam[t];
        const float c = cosf(0.5f * ang), s = sinf(0.5f * ang);
        const c32 u00 = U[l + 1][q][0], u01 = U[l + 1][q][1];
        const c32 u10 = U[l + 1][q][2], u11 = U[l + 1][q][3];
        W[l][q][0] = { u00.x * c + s * u01.y,  u00.y * c - s * u01.x };
        W[l][q][1] = { u01.x * c + s * u00.y,  u01.y * c - s * u00.x };
        W[l][q][2] = { u10.x * c + s * u11.y,  u10.y * c - s * u11.x };
        W[l][q][3] = { u11.x * c + s * u10.y,  u11.y * c - s * u10.x };
    }
    __syncthreads();   // U ready for layer 0; W ready well before layer 1

    float2 a[16];

    // Generic 4-gate pass: local bits (sh+3..sh), gates G[gi..gi+3] high->low bit.
    auto pass = [&](const c32 (*G)[4], int gi, int sh, bool four) {
        const int hi = (t >> sh) << (sh + 4);
        const int lo = t & ((1 << sh) - 1);
        #pragma unroll
        for (int j = 0; j < 16; ++j) a[j] = st[swz(hi | (j << sh) | lo)];
        if (four) { APPLYK(3, G[gi]); APPLYK(2, G[gi + 1]); }
        APPLYK(1, G[gi + 2]); APPLYK(0, G[gi + 3]);
        #pragma unroll
        for (int j = 0; j < 16; ++j) st[swz(hi | (j << sh) | lo)] = a[j];
        __syncthreads();
    };

    #pragma unroll 1
    for (int l = 0; l <= NLAYERS; ++l) {
        const c32 (*G)[4] = (l == 0) ? (const c32 (*)[4])U[0]
                                     : (const c32 (*)[4])W[l - 1];

        // ---- Pass A: bits 13..10 (q=0..3). Layer 0 inits |0> in registers;
        //      layers >=1 load with fused ring sign. ----
        if (l == 0) {
            #pragma unroll
            for (int j = 0; j < 16; ++j) a[j] = make_float2(0.f, 0.f);
            if (t == 0) a[0].x = 1.0f;
        } else {
            #pragma unroll
            for (int j = 0; j < 16; ++j) {
                const int i = (j << 10) | t;
                float2 v = st[swz(i)];
                const int rot = ((i << 1) | (i >> (NQ - 1))) & (DIM - 1);
                if (__popc(i & rot) & 1) { v.x = -v.x; v.y = -v.y; }
                a[j] = v;
            }
        }
        APPLYK(3, G[0]); APPLYK(2, G[1]); APPLYK(1, G[2]); APPLYK(0, G[3]);
        #pragma unroll
        for (int j = 0; j < 16; ++j) st[swz((j << 10) | t)] = a[j];
        __syncthreads();

        // ---- Pass B: bits 9..6 (q=4..7) ----
        pass(G, 4, 6, true);
        // ---- Pass C: bits 5..2 (q=8..11) ----
        pass(G, 8, 2, true);

        // ---- Pass D: bits 1..0 (q=12,13); last layer keeps result in regs ----
        #pragma unroll
        for (int j = 0; j < 16; ++j) a[j] = st[swz((t << 4) | j)];
        APPLYK(1, G[12]); APPLYK(0, G[13]);
        if (l < NLAYERS) {
            #pragma unroll
            for (int j = 0; j < 16; ++j) st[swz((t << 4) | j)] = a[j];
            __syncthreads();
        }
    }

    // ---- <Z^14> from registers (indices (t<<4)|j) + softmax ----
    float local = 0.0f;
    #pragma unroll
    for (int j = 0; j < 16; ++j) {
        const int i = (t << 4) | j;
        const float s = (__popc(i) & 1) ? -1.0f : 1.0f;
        local += s * (a[j].x * a[j].x + a[j].y * a[j].y);
    }
    #pragma unroll
    for (int off = 32; off > 0; off >>= 1)
        local += __shfl_down(local, off, 64);
    if ((t & 63) == 0) wsum[t >> 6] = local;
    __syncthreads();
    if (t == 0) {
        float v = 0.0f;
        #pragma unroll
        for (int i = 0; i < NTHREADS / 64; ++i) v += wsum[i];
        const float BETA = 1.0f;
        const float l0 = v * w[0] * BETA, l1 = v * w[1] * BETA;
        const float m  = fmaxf(l0, l1);
        const float e0 = __expf(l0 - m), e1 = __expf(l1 - m);
        const float inv = 1.0f / (e0 + e1);
        out[2 * b + 0] = e0 * inv;
        out[2 * b + 1] = e1 * inv;
    }
}

extern "C" void kernel_launch(void* const* d_in, const int* in_sizes, int n_in,
                              void* d_out, int out_size, void* d_ws, size_t ws_size,
                              hipStream_t stream) {
    const float* x     = (const float*)d_in[0];
    const float* theta = (const float*)d_in[1];
    const float* lam   = (const float*)d_in[2];
    const float* w     = (const float*)d_in[3];
    float* out = (float*)d_out;
    const int batch = in_sizes[0] / NQ;   // 2048
    pqc_kernel<<<batch, NTHREADS, 0, stream>>>(x, theta, lam, w, out);
}

// Round 3
// 1453.390 us; speedup vs baseline: 3.5823x; 3.5823x over previous
//
#include <hip/hip_runtime.h>
#include <math.h>

#define NQ        14
#define DIM       16384          // 2^14
#define NLAYERS   5
#define NTHREADS  1024

struct c32 { float x, y; };

// LDS amp-index swizzle (amp = float2 = 8B, bank-pair index = e & 15).
// e = i ^ i[7:4] ^ (i[9:8]<<2). Bijective (bits >=4 unchanged). Verified
// per pass pattern: within each 16-lane group e&15 hits all 16 values ->
// conflict-free b64 (<=2 lanes/bank).
__device__ __forceinline__ int swz(int i) {
    return i ^ ((i >> 4) & 15) ^ (((i >> 8) & 3) << 2);
}

// Apply gate {g0,g1;g2,g3} on local bit K of register amps a[16].
// All indices compile-time constants after unrolling (NO dynamic a[] access).
#define APPLYK(K, GP) { \
    const c32 g0 = (GP)[0], g1 = (GP)[1], g2 = (GP)[2], g3 = (GP)[3]; \
    _Pragma("unroll") \
    for (int m = 0; m < 8; ++m) { \
        const int r0 = ((m >> (K)) << ((K) + 1)) | (m & ((1 << (K)) - 1)); \
        const int r1 = r0 | (1 << (K)); \
        const float2 A0 = a[r0], A1 = a[r1]; \
        float2 B0, B1; \
        B0.x = g0.x*A0.x - g0.y*A0.y + g1.x*A1.x - g1.y*A1.y; \
        B0.y = g0.x*A0.y + g0.y*A0.x + g1.x*A1.y + g1.y*A1.x; \
        B1.x = g2.x*A0.x - g2.y*A0.y + g3.x*A1.x - g3.y*A1.y; \
        B1.y = g2.x*A0.y + g2.y*A0.x + g3.x*A1.y + g3.y*A1.x; \
        a[r0] = B0; a[r1] = B1; \
    } }

// Middle pass: window = bits SH+3..SH, 4 gates GI..GI+3 (high->low bit).
// Compile-time SH/GI -> fully static register indexing after inline.
template<int SH, int GI>
__device__ __forceinline__ void mid_pass(float2 (&a)[16], float2* st,
                                         const c32* Gf, int t) {
    const int hi = (t >> SH) << (SH + 4);
    const int lo = t & ((1 << SH) - 1);
    #pragma unroll
    for (int j = 0; j < 16; ++j) a[j] = st[swz(hi | (j << SH) | lo)];
    APPLYK(3, Gf + 4 * (GI + 0));
    APPLYK(2, Gf + 4 * (GI + 1));
    APPLYK(1, Gf + 4 * (GI + 2));
    APPLYK(0, Gf + 4 * (GI + 3));
    #pragma unroll
    for (int j = 0; j < 16; ++j) st[swz(hi | (j << SH) | lo)] = a[j];
    __syncthreads();
}

__global__ __launch_bounds__(NTHREADS, 4) void pqc_kernel(
    const float* __restrict__ x,      // (B, 14)
    const float* __restrict__ theta,  // (252,)
    const float* __restrict__ lam,    // (70,)
    const float* __restrict__ w,      // (1, 2)
    float* __restrict__ out)          // (B, 2)
{
    __shared__ float2 st[DIM];                 // 128 KiB state (swizzled)
    __shared__ c32 G[NLAYERS + 1][NQ][4];      // layer 0: RZ*RY*RX; 1..5: (RZ*RY*RX)@RX_enc
    __shared__ float wsum[NTHREADS / 64];

    const int t = threadIdx.x;
    const int b = blockIdx.x;

    // ---- Build all 84 fused gates (theta layout: 42*l + 3*q + c) ----
    if (t < (NLAYERS + 1) * NQ) {
        const int l = t / NQ, q = t % NQ;
        const float a0 = theta[3 * t + 0];
        const float a1 = theta[3 * t + 1];
        const float a2 = theta[3 * t + 2];
        const float cx = cosf(0.5f * a0), sx = sinf(0.5f * a0);
        const float cy = cosf(0.5f * a1), sy = sinf(0.5f * a1);
        const float cz = cosf(0.5f * a2), sz = sinf(0.5f * a2);
        // M = RY @ RX
        const c32 m00 = {  cy * cx,  sy * sx };
        const c32 m01 = { -sy * cx, -cy * sx };
        const c32 m10 = {  sy * cx, -cy * sx };
        const c32 m11 = {  cy * cx, -sy * sx };
        // U = RZ @ M
        c32 u00 = { cz * m00.x + sz * m00.y,  cz * m00.y - sz * m00.x };
        c32 u01 = { cz * m01.x + sz * m01.y,  cz * m01.y - sz * m01.x };
        c32 u10 = { cz * m10.x - sz * m10.y,  cz * m10.y + sz * m10.x };
        c32 u11 = { cz * m11.x - sz * m11.y,  cz * m11.y + sz * m11.x };
        if (l >= 1) {
            // Fuse preceding encoding RX: V = U @ RX(x*lam)
            const float ang = x[b * NQ + q] * lam[(l - 1) * NQ + q];
            const float c = cosf(0.5f * ang), s = sinf(0.5f * ang);
            const c32 v00 = { u00.x * c + s * u01.y,  u00.y * c - s * u01.x };
            const c32 v01 = { u01.x * c + s * u00.y,  u01.y * c - s * u00.x };
            const c32 v10 = { u10.x * c + s * u11.y,  u10.y * c - s * u11.x };
            const c32 v11 = { u11.x * c + s * u10.y,  u11.y * c - s * u10.x };
            u00 = v00; u01 = v01; u10 = v10; u11 = v11;
        }
        G[l][q][0] = u00; G[l][q][1] = u01; G[l][q][2] = u10; G[l][q][3] = u11;
    }
    __syncthreads();

    float2 a[16];

    #pragma unroll 1
    for (int l = 0; l <= NLAYERS; ++l) {
        const c32* Gf = &G[l][0][0];

        // ---- Pass A: bits 13..10 (q=0..3). l=0 inits |0> in regs;
        //      l>=1 loads with fused ring sign (after layer l-1). ----
        if (l == 0) {
            #pragma unroll
            for (int j = 0; j < 16; ++j) a[j] = make_float2(0.f, 0.f);
            if (t == 0) a[0].x = 1.0f;
        } else {
            #pragma unroll
            for (int j = 0; j < 16; ++j) {
                const int i = (j << 10) | t;
                const int rot = ((i << 1) | (i >> (NQ - 1))) & (DIM - 1);
                const float2 v = st[swz(i)];
                const float s = (__popc(i & rot) & 1) ? -1.0f : 1.0f;
                a[j].x = s * v.x; a[j].y = s * v.y;
            }
        }
        APPLYK(3, Gf + 0); APPLYK(2, Gf + 4); APPLYK(1, Gf + 8); APPLYK(0, Gf + 12);
        #pragma unroll
        for (int j = 0; j < 16; ++j) st[swz((j << 10) | t)] = a[j];
        __syncthreads();

        // ---- Pass B: bits 9..6 (q=4..7); Pass C: bits 5..2 (q=8..11) ----
        mid_pass<6, 4>(a, st, Gf, t);
        mid_pass<2, 8>(a, st, Gf, t);

        // ---- Pass D: bits 3..0 window, gates q=12,13 on bits 1,0.
        //      Last layer keeps the result in registers. ----
        #pragma unroll
        for (int j = 0; j < 16; ++j) a[j] = st[swz((t << 4) | j)];
        APPLYK(1, Gf + 4 * 12); APPLYK(0, Gf + 4 * 13);
        if (l < NLAYERS) {
            #pragma unroll
            for (int j = 0; j < 16; ++j) st[swz((t << 4) | j)] = a[j];
            __syncthreads();
        }
    }

    // ---- <Z^14> from registers (indices (t<<4)|j) + softmax ----
    float local = 0.0f;
    #pragma unroll
    for (int j = 0; j < 16; ++j) {
        const int i = (t << 4) | j;
        const float s = (__popc(i) & 1) ? -1.0f : 1.0f;
        local += s * (a[j].x * a[j].x + a[j].y * a[j].y);
    }
    #pragma unroll
    for (int off = 32; off > 0; off >>= 1)
        local += __shfl_down(local, off, 64);
    if ((t & 63) == 0) wsum[t >> 6] = local;
    __syncthreads();
    if (t == 0) {
        float v = 0.0f;
        #pragma unroll
        for (int i = 0; i < NTHREADS / 64; ++i) v += wsum[i];
        const float BETA = 1.0f;
        const float l0 = v * w[0] * BETA, l1 = v * w[1] * BETA;
        const float m  = fmaxf(l0, l1);
        const float e0 = __expf(l0 - m), e1 = __expf(l1 - m);
        const float inv = 1.0f / (e0 + e1);
        out[2 * b + 0] = e0 * inv;
        out[2 * b + 1] = e1 * inv;
    }
}

extern "C" void kernel_launch(void* const* d_in, const int* in_sizes, int n_in,
                              void* d_out, int out_size, void* d_ws, size_t ws_size,
                              hipStream_t stream) {
    const float* x     = (const float*)d_in[0];
    const float* theta = (const float*)d_in[1];
    const float* lam   = (const float*)d_in[2];
    const float* w     = (const float*)d_in[3];
    float* out = (float*)d_out;
    const int batch = in_sizes[0] / NQ;   // 2048
    pqc_kernel<<<batch, NTHREADS, 0, stream>>>(x, theta, lam, w, out);
}

// Round 4
// 1096.626 us; speedup vs baseline: 4.7478x; 1.3253x over previous
//
#include <hip/hip_runtime.h>
#include <math.h>

#define NQ        14
#define DIM       16384          // 2^14
#define NLAYERS   5
#define NTHREADS  1024

struct c32 { float x, y; };

__device__ __forceinline__ float2 f2(float s) { return make_float2(s, s); }
__device__ __forceinline__ float2 mul2(float2 a, float2 b) {
    return make_float2(a.x * b.x, a.y * b.y);
}
__device__ __forceinline__ float2 fma2(float2 a, float2 b, float2 c) {
    return make_float2(fmaf(a.x, b.x, c.x), fmaf(a.y, b.y, c.y));
}
// perp(A) = i*A as a real pair: (-A.y, A.x)
__device__ __forceinline__ float2 perp(float2 a) { return make_float2(-a.y, a.x); }

// LDS amp-index swizzle (amp = float2 = 8B, bank-pair index = e & 15).
// e = i ^ i[7:4] ^ (i[9:8]<<2). Bijective (bits >=4 unchanged). Conflict-free
// (<=2 lanes/bank) for all four pass access patterns.
__device__ __forceinline__ int swz(int i) {
    return i ^ ((i >> 4) & 15) ^ (((i >> 8) & 3) << 2);
}

// Apply gate {g0,g1;g2,g3} on local bit K of register amps a[16].
// Complex butterfly in packed-float2 form (maps to v_pk_fma_f32):
//   B0 = g0.x*A0 + g0.y*perp(A0) + g1.x*A1 + g1.y*perp(A1)
//   B1 = g2.x*A0 + g2.y*perp(A0) + g3.x*A1 + g3.y*perp(A1)
#define APPLYK(K, GP) { \
    const c32 g0 = (GP)[0], g1 = (GP)[1], g2 = (GP)[2], g3 = (GP)[3]; \
    _Pragma("unroll") \
    for (int m = 0; m < 8; ++m) { \
        const int r0 = ((m >> (K)) << ((K) + 1)) | (m & ((1 << (K)) - 1)); \
        const int r1 = r0 | (1 << (K)); \
        const float2 A0 = a[r0], A1 = a[r1]; \
        const float2 P0 = perp(A0), P1 = perp(A1); \
        float2 B0 = mul2(f2(g0.x), A0); \
        B0 = fma2(f2(g0.y), P0, B0); \
        B0 = fma2(f2(g1.x), A1, B0); \
        B0 = fma2(f2(g1.y), P1, B0); \
        float2 B1 = mul2(f2(g2.x), A0); \
        B1 = fma2(f2(g2.y), P0, B1); \
        B1 = fma2(f2(g3.x), A1, B1); \
        B1 = fma2(f2(g3.y), P1, B1); \
        a[r0] = B0; a[r1] = B1; \
    } }

// Middle pass: window = bits SH+3..SH, 4 gates GI..GI+3 (high->low bit).
template<int SH, int GI>
__device__ __forceinline__ void mid_pass(float2 (&a)[16], float2* st,
                                         const c32* Gf, int t) {
    const int hi = (t >> SH) << (SH + 4);
    const int lo = t & ((1 << SH) - 1);
    #pragma unroll
    for (int j = 0; j < 16; ++j) a[j] = st[swz(hi | (j << SH) | lo)];
    APPLYK(3, Gf + 4 * (GI + 0));
    APPLYK(2, Gf + 4 * (GI + 1));
    APPLYK(1, Gf + 4 * (GI + 2));
    APPLYK(0, Gf + 4 * (GI + 3));
    #pragma unroll
    for (int j = 0; j < 16; ++j) st[swz(hi | (j << SH) | lo)] = a[j];
    __syncthreads();
}

__global__ __launch_bounds__(NTHREADS)
__attribute__((amdgpu_waves_per_eu(4, 4)))   // 16-wave block -> exactly 4 waves/EU;
                                             // budget 128 VGPRs, stop the 64-cap spill
void pqc_kernel(
    const float* __restrict__ x,      // (B, 14)
    const float* __restrict__ theta,  // (252,)
    const float* __restrict__ lam,    // (70,)
    const float* __restrict__ w,      // (1, 2)
    float* __restrict__ out)          // (B, 2)
{
    __shared__ float2 st[DIM];                 // 128 KiB state (swizzled)
    __shared__ c32 G[NLAYERS + 1][NQ][4];      // l=0: RZ*RY*RX; l>=1: (RZ*RY*RX)@RX_enc
    __shared__ float wsum[NTHREADS / 64];

    const int t = threadIdx.x;
    const int b = blockIdx.x;

    // ---- Build all 84 fused gates (theta layout: 42*l + 3*q + c) ----
    if (t < (NLAYERS + 1) * NQ) {
        const int l = t / NQ, q = t % NQ;
        const float a0 = theta[3 * t + 0];
        const float a1 = theta[3 * t + 1];
        const float a2 = theta[3 * t + 2];
        const float cx = cosf(0.5f * a0), sx = sinf(0.5f * a0);
        const float cy = cosf(0.5f * a1), sy = sinf(0.5f * a1);
        const float cz = cosf(0.5f * a2), sz = sinf(0.5f * a2);
        // M = RY @ RX
        const c32 m00 = {  cy * cx,  sy * sx };
        const c32 m01 = { -sy * cx, -cy * sx };
        const c32 m10 = {  sy * cx, -cy * sx };
        const c32 m11 = {  cy * cx, -sy * sx };
        // U = RZ @ M
        c32 u00 = { cz * m00.x + sz * m00.y,  cz * m00.y - sz * m00.x };
        c32 u01 = { cz * m01.x + sz * m01.y,  cz * m01.y - sz * m01.x };
        c32 u10 = { cz * m10.x - sz * m10.y,  cz * m10.y + sz * m10.x };
        c32 u11 = { cz * m11.x - sz * m11.y,  cz * m11.y + sz * m11.x };
        if (l >= 1) {
            // Fuse preceding encoding RX: V = U @ RX(x*lam)
            const float ang = x[b * NQ + q] * lam[(l - 1) * NQ + q];
            const float c = cosf(0.5f * ang), s = sinf(0.5f * ang);
            const c32 v00 = { u00.x * c + s * u01.y,  u00.y * c - s * u01.x };
            const c32 v01 = { u01.x * c + s * u00.y,  u01.y * c - s * u00.x };
            const c32 v10 = { u10.x * c + s * u11.y,  u10.y * c - s * u11.x };
            const c32 v11 = { u11.x * c + s * u10.y,  u11.y * c - s * u10.x };
            u00 = v00; u01 = v01; u10 = v10; u11 = v11;
        }
        G[l][q][0] = u00; G[l][q][1] = u01; G[l][q][2] = u10; G[l][q][3] = u11;
    }
    __syncthreads();

    float2 a[16];

    #pragma unroll 1
    for (int l = 0; l <= NLAYERS; ++l) {
        const c32* Gf = &G[l][0][0];

        // ---- Pass A: bits 13..10 (q=0..3). l=0 inits |0> in regs;
        //      l>=1 loads with fused ring sign. ----
        if (l == 0) {
            #pragma unroll
            for (int j = 0; j < 16; ++j) a[j] = make_float2(0.f, 0.f);
            if (t == 0) a[0].x = 1.0f;
        } else {
            #pragma unroll
            for (int j = 0; j < 16; ++j) {
                const int i = (j << 10) | t;
                const int rot = ((i << 1) | (i >> (NQ - 1))) & (DIM - 1);
                const float2 v = st[swz(i)];
                const float s = (__popc(i & rot) & 1) ? -1.0f : 1.0f;
                a[j] = mul2(f2(s), v);
            }
        }
        APPLYK(3, Gf + 0); APPLYK(2, Gf + 4); APPLYK(1, Gf + 8); APPLYK(0, Gf + 12);
        #pragma unroll
        for (int j = 0; j < 16; ++j) st[swz((j << 10) | t)] = a[j];
        __syncthreads();

        // ---- Pass B: bits 9..6 (q=4..7); Pass C: bits 5..2 (q=8..11) ----
        mid_pass<6, 4>(a, st, Gf, t);
        mid_pass<2, 8>(a, st, Gf, t);

        // ---- Pass D: bits 3..0 window, gates q=12,13 on bits 1,0.
        //      Last layer keeps the result in registers. ----
        #pragma unroll
        for (int j = 0; j < 16; ++j) a[j] = st[swz((t << 4) | j)];
        APPLYK(1, Gf + 4 * 12); APPLYK(0, Gf + 4 * 13);
        if (l < NLAYERS) {
            #pragma unroll
            for (int j = 0; j < 16; ++j) st[swz((t << 4) | j)] = a[j];
            __syncthreads();
        }
    }

    // ---- <Z^14> from registers (indices (t<<4)|j) + softmax ----
    float local = 0.0f;
    #pragma unroll
    for (int j = 0; j < 16; ++j) {
        const int i = (t << 4) | j;
        const float s = (__popc(i) & 1) ? -1.0f : 1.0f;
        local += s * (a[j].x * a[j].x + a[j].y * a[j].y);
    }
    #pragma unroll
    for (int off = 32; off > 0; off >>= 1)
        local += __shfl_down(local, off, 64);
    if ((t & 63) == 0) wsum[t >> 6] = local;
    __syncthreads();
    if (t == 0) {
        float v = 0.0f;
        #pragma unroll
        for (int i = 0; i < NTHREADS / 64; ++i) v += wsum[i];
        const float BETA = 1.0f;
        const float l0 = v * w[0] * BETA, l1 = v * w[1] * BETA;
        const float m  = fmaxf(l0, l1);
        const float e0 = __expf(l0 - m), e1 = __expf(l1 - m);
        const float inv = 1.0f / (e0 + e1);
        out[2 * b + 0] = e0 * inv;
        out[2 * b + 1] = e1 * inv;
    }
}

extern "C" void kernel_launch(void* const* d_in, const int* in_sizes, int n_in,
                              void* d_out, int out_size, void* d_ws, size_t ws_size,
                              hipStream_t stream) {
    const float* x     = (const float*)d_in[0];
    const float* theta = (const float*)d_in[1];
    const float* lam   = (const float*)d_in[2];
    const float* w     = (const float*)d_in[3];
    float* out = (float*)d_out;
    const int batch = in_sizes[0] / NQ;   // 2048
    pqc_kernel<<<batch, NTHREADS, 0, stream>>>(x, theta, lam, w, out);
}

// Round 5
// 550.133 us; speedup vs baseline: 9.4641x; 1.9934x over previous
//
#include <hip/hip_runtime.h>
#include <math.h>

#define NQ        14
#define DIM       16384          // 2^14
#define NLAYERS   5
#define NTHREADS  1024

struct c32 { float x, y; };

__device__ __forceinline__ float2 f2(float s) { return make_float2(s, s); }
__device__ __forceinline__ float2 mul2(float2 a, float2 b) {
    return make_float2(a.x * b.x, a.y * b.y);
}
__device__ __forceinline__ float2 fma2(float2 a, float2 b, float2 c) {
    return make_float2(fmaf(a.x, b.x, c.x), fmaf(a.y, b.y, c.y));
}
// perp(A) = i*A as a real pair
__device__ __forceinline__ float2 perp(float2 a) { return make_float2(-a.y, a.x); }
__device__ __forceinline__ c32 cmul(c32 a, c32 b) {
    return { a.x * b.x - a.y * b.y, a.x * b.y + a.y * b.x };
}

// LDS amp-index swizzle (amp = float2 = 8B, bank-pair index = e & 15).
// e = i ^ i[7:4] ^ (i[9:8]<<2). Bijective. Hand-verified conflict-free
// (16 distinct bank-pairs per 16-lane group) for the init store and passes
// P1/P2/P3/P5; P4 (sh=2) is 2-way (~free per m136).
__device__ __forceinline__ int swz(int i) {
    return i ^ ((i >> 4) & 15) ^ (((i >> 8) & 3) << 2);
}

// Complex butterfly, packed-float2 form (v_pk_fma_f32):
#define BUTTERFLY(GP, A0, A1, B0, B1) { \
    const c32 g0 = (GP)[0], g1 = (GP)[1], g2 = (GP)[2], g3 = (GP)[3]; \
    const float2 P0 = perp(A0), P1 = perp(A1); \
    B0 = mul2(f2(g0.x), A0); B0 = fma2(f2(g0.y), P0, B0); \
    B0 = fma2(f2(g1.x), A1, B0); B0 = fma2(f2(g1.y), P1, B0); \
    B1 = mul2(f2(g2.x), A0); B1 = fma2(f2(g2.y), P0, B1); \
    B1 = fma2(f2(g3.x), A1, B1); B1 = fma2(f2(g3.y), P1, B1); }

// Gate on local bit K of a[8] (indices compile-time after unroll).
#define APPLY8(K, GP) { \
    _Pragma("unroll") \
    for (int m = 0; m < 4; ++m) { \
        const int r0 = ((m >> (K)) << ((K) + 1)) | (m & ((1 << (K)) - 1)); \
        const int r1 = r0 | (1 << (K)); \
        float2 B0, B1; BUTTERFLY(GP, a[r0], a[r1], B0, B1); \
        a[r0] = B0; a[r1] = B1; } }

// Gate on local bit K of a4[4].
#define APPLY4(K, GP) { \
    _Pragma("unroll") \
    for (int m = 0; m < 2; ++m) { \
        const int r0 = ((m >> (K)) << ((K) + 1)) | (m & ((1 << (K)) - 1)); \
        const int r1 = r0 | (1 << (K)); \
        float2 B0, B1; BUTTERFLY(GP, a4[r0], a4[r1], B0, B1); \
        a4[r0] = B0; a4[r1] = B1; } }

// 3-bit window pass: bits SH+2..SH, gates GI,GI+1,GI+2 (high->low bit).
template<int SH, int GI>
__device__ __forceinline__ void pass3(float2* st, const c32* Gf, int t) {
    #pragma unroll 1
    for (int w = 0; w < 2; ++w) {
        float2 a[8];
        const int p  = (w << 10) | t;
        const int hi = (p >> SH) << (SH + 3);
        const int lo = p & ((1 << SH) - 1);
        #pragma unroll
        for (int j = 0; j < 8; ++j) a[j] = st[swz(hi | (j << SH) | lo)];
        APPLY8(2, Gf + 4 * (GI + 0));
        APPLY8(1, Gf + 4 * (GI + 1));
        APPLY8(0, Gf + 4 * (GI + 2));
        #pragma unroll
        for (int j = 0; j < 8; ++j) st[swz(hi | (j << SH) | lo)] = a[j];
    }
    __syncthreads();
}

// Top pass (bits 13..11, gates q=0,1,2) with fused ring sign on load.
__device__ __forceinline__ void pass_top(float2* st, const c32* Gf, int t) {
    #pragma unroll 1
    for (int w = 0; w < 2; ++w) {
        float2 a[8];
        const int p = (w << 10) | t;
        #pragma unroll
        for (int j = 0; j < 8; ++j) {
            const int i = (j << 11) | p;
            const float2 v = st[swz(i)];
            const int rot = ((i << 1) | (i >> (NQ - 1))) & (DIM - 1);
            const float s = (__popc(i & rot) & 1) ? -1.0f : 1.0f;
            a[j] = mul2(f2(s), v);
        }
        APPLY8(2, Gf + 0);
        APPLY8(1, Gf + 4);
        APPLY8(0, Gf + 8);
        #pragma unroll
        for (int j = 0; j < 8; ++j) st[swz((j << 11) | p)] = a[j];
    }
    __syncthreads();
}

// Bottom pass (bits 1..0, gates q=12,13). LAST: accumulate <Z^14> instead of store.
template<bool LAST>
__device__ __forceinline__ void pass_bot(float2* st, const c32* Gf, int t, float& local) {
    #pragma unroll 1
    for (int w = 0; w < 4; ++w) {
        float2 a4[4];
        const int base = ((w << 10) | t) << 2;
        #pragma unroll
        for (int j = 0; j < 4; ++j) a4[j] = st[swz(base | j)];
        APPLY4(1, Gf + 4 * 12);
        APPLY4(0, Gf + 4 * 13);
        if (LAST) {
            #pragma unroll
            for (int j = 0; j < 4; ++j) {
                const float s = (__popc(base | j) & 1) ? -1.0f : 1.0f;
                local = fmaf(s * a4[j].x, a4[j].x, local);
                local = fmaf(s * a4[j].y, a4[j].y, local);
            }
        } else {
            #pragma unroll
            for (int j = 0; j < 4; ++j) st[swz(base | j)] = a4[j];
        }
    }
    if (!LAST) __syncthreads();
}

__global__ __launch_bounds__(NTHREADS) void pqc_kernel(
    const float* __restrict__ x,      // (B, 14)
    const float* __restrict__ theta,  // (252,)
    const float* __restrict__ lam,    // (70,)
    const float* __restrict__ w,      // (1, 2)
    float* __restrict__ out)          // (B, 2)
{
    __shared__ float2 st[DIM];                 // 128 KiB state (swizzled)
    __shared__ c32 G[NLAYERS + 1][NQ][4];      // l=0: RZ*RY*RX; l>=1: (RZ*RY*RX)@RX_enc
    __shared__ float wsum[NTHREADS / 64];

    const int t = threadIdx.x;
    const int b = blockIdx.x;

    // ---- Build all 84 fused gates (theta layout: 42*l + 3*q + c) ----
    if (t < (NLAYERS + 1) * NQ) {
        const int l = t / NQ, q = t % NQ;
        const float a0 = theta[3 * t + 0];
        const float a1 = theta[3 * t + 1];
        const float a2 = theta[3 * t + 2];
        const float cx = cosf(0.5f * a0), sx = sinf(0.5f * a0);
        const float cy = cosf(0.5f * a1), sy = sinf(0.5f * a1);
        const float cz = cosf(0.5f * a2), sz = sinf(0.5f * a2);
        // M = RY @ RX
        const c32 m00 = {  cy * cx,  sy * sx };
        const c32 m01 = { -sy * cx, -cy * sx };
        const c32 m10 = {  sy * cx, -cy * sx };
        const c32 m11 = {  cy * cx, -sy * sx };
        // U = RZ @ M
        c32 u00 = { cz * m00.x + sz * m00.y,  cz * m00.y - sz * m00.x };
        c32 u01 = { cz * m01.x + sz * m01.y,  cz * m01.y - sz * m01.x };
        c32 u10 = { cz * m10.x - sz * m10.y,  cz * m10.y + sz * m10.x };
        c32 u11 = { cz * m11.x - sz * m11.y,  cz * m11.y + sz * m11.x };
        if (l >= 1) {
            // Fuse preceding encoding RX: V = U @ RX(x*lam)
            const float ang = x[b * NQ + q] * lam[(l - 1) * NQ + q];
            const float c = cosf(0.5f * ang), s = sinf(0.5f * ang);
            const c32 v00 = { u00.x * c + s * u01.y,  u00.y * c - s * u01.x };
            const c32 v01 = { u01.x * c + s * u00.y,  u01.y * c - s * u00.x };
            const c32 v10 = { u10.x * c + s * u11.y,  u10.y * c - s * u11.x };
            const c32 v11 = { u11.x * c + s * u10.y,  u11.y * c - s * u10.x };
            u00 = v00; u01 = v01; u10 = v10; u11 = v11;
        }
        G[l][q][0] = u00; G[l][q][1] = u01; G[l][q][2] = u10; G[l][q][3] = u11;
    }
    __syncthreads();

    // ---- Layer 0 analytically: amp(i) = prod_q U0[q][bit_{13-q}(i)][0] ----
    // i = (t<<4) | j: qubits 0..9 from t (bit 9-q of t), qubits 10..13 from j.
    {
        c32 pref = G[0][0][((t >> 9) & 1) ? 2 : 0];
        #pragma unroll
        for (int q = 1; q <= 9; ++q)
            pref = cmul(pref, G[0][q][((t >> (9 - q)) & 1) ? 2 : 0]);
        #pragma unroll
        for (int j = 0; j < 16; ++j) {
            c32 v = pref;
            #pragma unroll
            for (int q = 10; q <= 13; ++q)
                v = cmul(v, G[0][q][((j >> (13 - q)) & 1) ? 2 : 0]);
            st[swz((t << 4) | j)] = make_float2(v.x, v.y);
        }
    }
    __syncthreads();

    // ---- Layers 1..5: ring sign (fused in pass_top) + 14 gates in 5 passes ----
    float local = 0.0f;
    #pragma unroll 1
    for (int l = 1; l <= NLAYERS; ++l) {
        const c32* Gf = &G[l][0][0];
        pass_top(st, Gf, t);          // bits 13..11, q=0..2, + ring sign
        pass3<8, 3>(st, Gf, t);       // bits 10..8,  q=3..5
        pass3<5, 6>(st, Gf, t);       // bits  7..5,  q=6..8
        pass3<2, 9>(st, Gf, t);       // bits  4..2,  q=9..11
        if (l < NLAYERS) pass_bot<false>(st, Gf, t, local);
        else             pass_bot<true >(st, Gf, t, local);   // + <Z^14> accum
    }

    // ---- Reduce + softmax ----
    #pragma unroll
    for (int off = 32; off > 0; off >>= 1)
        local += __shfl_down(local, off, 64);
    if ((t & 63) == 0) wsum[t >> 6] = local;
    __syncthreads();
    if (t == 0) {
        float v = 0.0f;
        #pragma unroll
        for (int i = 0; i < NTHREADS / 64; ++i) v += wsum[i];
        const float BETA = 1.0f;
        const float l0 = v * w[0] * BETA, l1 = v * w[1] * BETA;
        const float m  = fmaxf(l0, l1);
        const float e0 = __expf(l0 - m), e1 = __expf(l1 - m);
        const float inv = 1.0f / (e0 + e1);
        out[2 * b + 0] = e0 * inv;
        out[2 * b + 1] = e1 * inv;
    }
}

extern "C" void kernel_launch(void* const* d_in, const int* in_sizes, int n_in,
                              void* d_out, int out_size, void* d_ws, size_t ws_size,
                              hipStream_t stream) {
    const float* x     = (const float*)d_in[0];
    const float* theta = (const float*)d_in[1];
    const float* lam   = (const float*)d_in[2];
    const float* w     = (const float*)d_in[3];
    float* out = (float*)d_out;
    const int batch = in_sizes[0] / NQ;   // 2048
    pqc_kernel<<<batch, NTHREADS, 0, stream>>>(x, theta, lam, w, out);
}

// Round 6
// 508.087 us; speedup vs baseline: 10.2473x; 1.0828x over previous
//
#include <hip/hip_runtime.h>
#include <math.h>

#define NQ        14
#define DIM       16384          // 2^14
#define NLAYERS   5
#define NTHREADS  512            // 32 amps/thread

typedef float vf2 __attribute__((ext_vector_type(2)));
struct c32 { float x, y; };

// GF(2)-LINEAR layout: L(i) = i ^ sigma(i), sigma image in bits 3:0, inputs bits>=4.
// Linear => L(a^b) = L(a)^L(b): pass addresses = thread_base ^ compile-time const.
// Conflict-free (bank-pair = b ^ const within each aligned 16-lane group) for all
// three pass patterns and the init store (hand-verified).
__host__ __device__ constexpr int lswz(int i) {
    return i ^ ((i >> 4) & 15) ^ ((i >> 8) & 15) ^ ((i >> 12) & 3);
}
// Ring-sign parity of the window-internal adjacent pairs of 5-bit j (bits 13..9).
__host__ __device__ constexpr unsigned sjc(int j) {
    return (((j >> 4) & (j >> 3)) ^ ((j >> 3) & (j >> 2)) ^
            ((j >> 2) & (j >> 1)) ^ ((j >> 1) & j)) & 1u;
}

__device__ __forceinline__ c32 cmul(c32 a, c32 b) {
    return { a.x * b.x - a.y * b.y, a.x * b.y + a.y * b.x };
}

// Complex butterfly on packed pairs (targets v_pk_fma_f32 via <2 x float>).
__device__ __forceinline__ void bf(const c32 (&g)[4], vf2& A0, vf2& A1) {
    const vf2 P0 = { -A0.y, A0.x };
    const vf2 P1 = { -A1.y, A1.x };
    const vf2 B0 = g[0].x * A0 + g[0].y * P0 + g[1].x * A1 + g[1].y * P1;
    const vf2 B1 = g[2].x * A0 + g[2].y * P0 + g[3].x * A1 + g[3].y * P1;
    A0 = B0; A1 = B1;
}

// Gate on local bit K of a[32] / aa[16]; all indices compile-time after unroll.
#define APPLY32(K, GG) { _Pragma("unroll") \
    for (int mm = 0; mm < 16; ++mm) { \
        const int r0 = ((mm >> (K)) << ((K) + 1)) | (mm & ((1 << (K)) - 1)); \
        bf(GG, a[r0], a[r0 | (1 << (K))]); } }
#define APPLY16(K, GG) { _Pragma("unroll") \
    for (int mm = 0; mm < 8; ++mm) { \
        const int r0 = ((mm >> (K)) << ((K) + 1)) | (mm & ((1 << (K)) - 1)); \
        bf(GG, aa[r0], aa[r0 | (1 << (K))]); } }

__attribute__((amdgpu_flat_work_group_size(NTHREADS, NTHREADS),
               amdgpu_waves_per_eu(2, 2)))           // exactly 2 waves/EU -> 256 VGPR budget
__global__ void pqc_kernel(
    const float* __restrict__ x,      // (B, 14)
    const float* __restrict__ theta,  // (252,)
    const float* __restrict__ lam,    // (70,)
    const float* __restrict__ w,      // (1, 2)
    float* __restrict__ out)          // (B, 2)
{
    __shared__ vf2 st[DIM];                    // 128 KiB state, layout L(i)
    __shared__ c32 G[NLAYERS + 1][NQ][4];      // l=0: RZ*RY*RX; l>=1: (RZ*RY*RX)@RX_enc
    __shared__ float wsum[NTHREADS / 64];

    const int t = threadIdx.x;
    const int b = blockIdx.x;
    char* stb = (char*)st;

    // ---- Build all 84 fused gates (theta layout: 42*l + 3*q + c) ----
    if (t < (NLAYERS + 1) * NQ) {
        const int l = t / NQ, q = t % NQ;
        const float a0 = theta[3 * t + 0];
        const float a1 = theta[3 * t + 1];
        const float a2 = theta[3 * t + 2];
        const float cx = cosf(0.5f * a0), sx = sinf(0.5f * a0);
        const float cy = cosf(0.5f * a1), sy = sinf(0.5f * a1);
        const float cz = cosf(0.5f * a2), sz = sinf(0.5f * a2);
        const c32 m00 = {  cy * cx,  sy * sx };
        const c32 m01 = { -sy * cx, -cy * sx };
        const c32 m10 = {  sy * cx, -cy * sx };
        const c32 m11 = {  cy * cx, -sy * sx };
        c32 u00 = { cz * m00.x + sz * m00.y,  cz * m00.y - sz * m00.x };
        c32 u01 = { cz * m01.x + sz * m01.y,  cz * m01.y - sz * m01.x };
        c32 u10 = { cz * m10.x - sz * m10.y,  cz * m10.y + sz * m10.x };
        c32 u11 = { cz * m11.x - sz * m11.y,  cz * m11.y + sz * m11.x };
        if (l >= 1) {
            const float ang = x[b * NQ + q] * lam[(l - 1) * NQ + q];
            const float c = cosf(0.5f * ang), s = sinf(0.5f * ang);
            const c32 v00 = { u00.x * c + s * u01.y,  u00.y * c - s * u01.x };
            const c32 v01 = { u01.x * c + s * u00.y,  u01.y * c - s * u00.x };
            const c32 v10 = { u10.x * c + s * u11.y,  u10.y * c - s * u11.x };
            const c32 v11 = { u11.x * c + s * u10.y,  u11.y * c - s * u10.x };
            u00 = v00; u01 = v01; u10 = v10; u11 = v11;
        }
        G[l][q][0] = u00; G[l][q][1] = u01; G[l][q][2] = u10; G[l][q][3] = u11;
    }
    __syncthreads();

    // ---- Per-thread bases (byte offsets) and ring-sign masks ----
    const int base1 = lswz(t) << 3;                                   // P1: i=(j<<9)|t
    const int base2 = lswz(((t & 0x1F0) << 5) | (t & 15)) << 3;       // P2
    const int base3 = lswz(t << 4) << 3;                              // P3 / init
    const unsigned Pp  = (unsigned)(__popc(t & (t >> 1) & 0xFF) & 1); // pairs (8,7)..(1,0) of t
    const unsigned t8 = (t >> 8) & 1u, tb0 = t & 1u;
    const unsigned M00 =  Pp              << 31;
    const unsigned M10 = (Pp ^ t8)        << 31;
    const unsigned M01 = (Pp ^ tb0)       << 31;
    const unsigned M11 = (Pp ^ t8 ^ tb0)  << 31;

    // ---- Layer 0 analytically: |0..0> through U0 is a tensor product ----
    // i = (v<<13)|(t<<4)|j : qubit0<-v, qubits1..9<-t bits 8..0, qubits10..13<-j.
    {
        c32 pref = G[0][1][((t >> 8) & 1) ? 2 : 0];
        #pragma unroll
        for (int qq = 2; qq <= 9; ++qq)
            pref = cmul(pref, G[0][qq][((t >> (9 - qq)) & 1) ? 2 : 0]);
        const c32 pv[2] = { cmul(pref, G[0][0][0]), cmul(pref, G[0][0][2]) };
        c32 p01[4], p23[4];
        #pragma unroll
        for (int k = 0; k < 4; ++k) {
            p01[k] = cmul(G[0][10][(k >> 1) ? 2 : 0], G[0][11][(k & 1) ? 2 : 0]);
            p23[k] = cmul(G[0][12][(k >> 1) ? 2 : 0], G[0][13][(k & 1) ? 2 : 0]);
        }
        #pragma unroll
        for (int v = 0; v < 2; ++v)
            #pragma unroll
            for (int j = 0; j < 16; ++j) {
                const c32 av = cmul(cmul(pv[v], p01[j >> 2]), p23[j & 3]);
                *(vf2*)(stb + (base3 ^ (lswz(v << 13) << 3) ^ (j << 3))) = vf2{ av.x, av.y };
            }
    }
    __syncthreads();

    float se = 0.f, so = 0.f;

    #pragma unroll 1
    for (int l = 1; l <= NLAYERS; ++l) {
        // ---- P1: bits 13..9 (q0..q4), ring sign fused on load ----
        {
            c32 ga[5][4];
            #pragma unroll
            for (int q = 0; q < 5; ++q) {
                ga[q][0] = G[l][q][0]; ga[q][1] = G[l][q][1];
                ga[q][2] = G[l][q][2]; ga[q][3] = G[l][q][3];
            }
            vf2 a[32];
            #pragma unroll
            for (int j = 0; j < 32; ++j) {
                const vf2 v = *(const vf2*)(stb + (base1 ^ (lswz(j << 9) << 3)));
                const unsigned mj = ((j & 1) ? (((j >> 4) & 1) ? M11 : M10)
                                             : (((j >> 4) & 1) ? M01 : M00))
                                    ^ (sjc(j) << 31);
                a[j] = vf2{ __uint_as_float(__float_as_uint(v.x) ^ mj),
                            __uint_as_float(__float_as_uint(v.y) ^ mj) };
            }
            APPLY32(4, ga[0]); APPLY32(3, ga[1]); APPLY32(2, ga[2]);
            APPLY32(1, ga[3]); APPLY32(0, ga[4]);
            #pragma unroll
            for (int j = 0; j < 32; ++j)
                *(vf2*)(stb + (base1 ^ (lswz(j << 9) << 3))) = a[j];
        }
        __syncthreads();

        // ---- P2: bits 8..4 (q5..q9) ----
        {
            c32 ga[5][4];
            #pragma unroll
            for (int q = 0; q < 5; ++q) {
                ga[q][0] = G[l][5 + q][0]; ga[q][1] = G[l][5 + q][1];
                ga[q][2] = G[l][5 + q][2]; ga[q][3] = G[l][5 + q][3];
            }
            vf2 a[32];
            #pragma unroll
            for (int j = 0; j < 32; ++j)
                a[j] = *(const vf2*)(stb + (base2 ^ (lswz(j << 4) << 3)));
            APPLY32(4, ga[0]); APPLY32(3, ga[1]); APPLY32(2, ga[2]);
            APPLY32(1, ga[3]); APPLY32(0, ga[4]);
            #pragma unroll
            for (int j = 0; j < 32; ++j)
                *(vf2*)(stb + (base2 ^ (lswz(j << 4) << 3))) = a[j];
        }
        __syncthreads();

        // ---- P3: bits 3..0 (q10..q13); last layer: fold in <Z^14> ----
        {
            c32 gb[4][4];
            #pragma unroll
            for (int q = 0; q < 4; ++q) {
                gb[q][0] = G[l][10 + q][0]; gb[q][1] = G[l][10 + q][1];
                gb[q][2] = G[l][10 + q][2]; gb[q][3] = G[l][10 + q][3];
            }
            #pragma unroll
            for (int v = 0; v < 2; ++v) {
                vf2 aa[16];
                #pragma unroll
                for (int j = 0; j < 16; ++j)
                    aa[j] = *(const vf2*)(stb + (base3 ^ (lswz(v << 13) << 3) ^ (j << 3)));
                APPLY16(3, gb[0]); APPLY16(2, gb[1]);
                APPLY16(1, gb[2]); APPLY16(0, gb[3]);
                if (l < NLAYERS) {
                    #pragma unroll
                    for (int j = 0; j < 16; ++j)
                        *(vf2*)(stb + (base3 ^ (lswz(v << 13) << 3) ^ (j << 3))) = aa[j];
                } else {
                    #pragma unroll
                    for (int j = 0; j < 16; ++j) {
                        const float d = fmaf(aa[j].x, aa[j].x, aa[j].y * aa[j].y);
                        if (((v ^ __popc(j)) & 1) == 0) se += d; else so += d;
                    }
                }
            }
        }
        if (l < NLAYERS) __syncthreads();
    }

    // ---- Reduce + softmax ----
    float local = (__popc(t) & 1) ? (so - se) : (se - so);
    #pragma unroll
    for (int off = 32; off > 0; off >>= 1)
        local += __shfl_down(local, off, 64);
    if ((t & 63) == 0) wsum[t >> 6] = local;
    __syncthreads();
    if (t == 0) {
        float v = 0.0f;
        #pragma unroll
        for (int i = 0; i < NTHREADS / 64; ++i) v += wsum[i];
        const float BETA = 1.0f;
        const float l0 = v * w[0] * BETA, l1 = v * w[1] * BETA;
        const float m  = fmaxf(l0, l1);
        const float e0 = __expf(l0 - m), e1 = __expf(l1 - m);
        const float inv = 1.0f / (e0 + e1);
        out[2 * b + 0] = e0 * inv;
        out[2 * b + 1] = e1 * inv;
    }
}

extern "C" void kernel_launch(void* const* d_in, const int* in_sizes, int n_in,
                              void* d_out, int out_size, void* d_ws, size_t ws_size,
                              hipStream_t stream) {
    const float* x     = (const float*)d_in[0];
    const float* theta = (const float*)d_in[1];
    const float* lam   = (const float*)d_in[2];
    const float* w     = (const float*)d_in[3];
    float* out = (float*)d_out;
    const int batch = in_sizes[0] / NQ;   // 2048
    pqc_kernel<<<batch, NTHREADS, 0, stream>>>(x, theta, lam, w, out);
}

// Round 7
// 395.942 us; speedup vs baseline: 13.1497x; 1.2832x over previous
//
#include <hip/hip_runtime.h>
#include <math.h>

#define NQ        14
#define DIM       16384          // 2^14
#define NLAYERS   5
#define NTHREADS  512            // 32 amps/thread

typedef float vf2 __attribute__((ext_vector_type(2)));
struct c32 { float x, y; };

// GF(2)-LINEAR layout: L(i) = i ^ sigma(i), sigma image in bits 3:0, inputs bits>=4.
// Linear => L(a^b) = L(a)^L(b): pass addresses = thread_base ^ compile-time const.
// Conflict-free for all three pass patterns and the init store (hand-verified, r6).
__host__ __device__ constexpr int lswz(int i) {
    return i ^ ((i >> 4) & 15) ^ ((i >> 8) & 15) ^ ((i >> 12) & 3);
}
// Ring-sign parity of the window-internal adjacent pairs of 5-bit j (bits 13..9).
__host__ __device__ constexpr unsigned sjc(int j) {
    return (((j >> 4) & (j >> 3)) ^ ((j >> 3) & (j >> 2)) ^
            ((j >> 2) & (j >> 1)) ^ ((j >> 1) & j)) & 1u;
}

__device__ __forceinline__ c32 cmul(c32 a, c32 b) {
    return { a.x * b.x - a.y * b.y, a.x * b.y + a.y * b.x };
}

// Complex butterfly in 8 VOP3P instrs. g* = (re,im) coefficient pairs in VGPR
// pairs. Coefficient broadcast via op_sel/op_sel_hi=[k,k]; perp(A)=(-A.y,A.x)
// via op_sel:[1],op_sel_hi:[0],neg_lo:[1] on the A operand — no aux instrs.
//   B0 = g0.x*A0 + g0.y*perp(A0) + g1.x*A1 + g1.y*perp(A1)
//   B1 = g2.x*A0 + g2.y*perp(A0) + g3.x*A1 + g3.y*perp(A1)
__device__ __forceinline__ void bf(vf2 g0, vf2 g1, vf2 g2, vf2 g3,
                                   vf2& A0, vf2& A1) {
    vf2 b0, b1;
    asm("v_pk_mul_f32 %0, %3, %7 op_sel:[1,1] op_sel_hi:[1,0] neg_lo:[0,1] neg_hi:[0,0]\n\t"
        "v_pk_mul_f32 %1, %5, %7 op_sel:[1,1] op_sel_hi:[1,0] neg_lo:[0,1] neg_hi:[0,0]\n\t"
        "v_pk_fma_f32 %0, %3, %7, %0 op_sel:[0,0,0] op_sel_hi:[0,1,1]\n\t"
        "v_pk_fma_f32 %1, %5, %7, %1 op_sel:[0,0,0] op_sel_hi:[0,1,1]\n\t"
        "v_pk_fma_f32 %0, %2, %6, %0 op_sel:[1,1,0] op_sel_hi:[1,0,1] neg_lo:[0,1,0] neg_hi:[0,0,0]\n\t"
        "v_pk_fma_f32 %1, %4, %6, %1 op_sel:[1,1,0] op_sel_hi:[1,0,1] neg_lo:[0,1,0] neg_hi:[0,0,0]\n\t"
        "v_pk_fma_f32 %0, %2, %6, %0 op_sel:[0,0,0] op_sel_hi:[0,1,1]\n\t"
        "v_pk_fma_f32 %1, %4, %6, %1 op_sel:[0,0,0] op_sel_hi:[0,1,1]"
        : "=&v"(b0), "=&v"(b1)
        : "v"(g0), "v"(g1), "v"(g2), "v"(g3), "v"(A0), "v"(A1));
    A0 = b0; A1 = b1;
}

// Gate on local bit K of a[32] / aa[16]; indices compile-time after unroll.
#define APPLY32(K, GG) { _Pragma("unroll") \
    for (int mm = 0; mm < 16; ++mm) { \
        const int r0 = ((mm >> (K)) << ((K) + 1)) | (mm & ((1 << (K)) - 1)); \
        bf((GG)[0], (GG)[1], (GG)[2], (GG)[3], a[r0], a[r0 | (1 << (K))]); } }
#define APPLY16(K, GG) { _Pragma("unroll") \
    for (int mm = 0; mm < 8; ++mm) { \
        const int r0 = ((mm >> (K)) << ((K) + 1)) | (mm & ((1 << (K)) - 1)); \
        bf((GG)[0], (GG)[1], (GG)[2], (GG)[3], aa[r0], aa[r0 | (1 << (K))]); } }

__attribute__((amdgpu_flat_work_group_size(NTHREADS, NTHREADS),
               amdgpu_waves_per_eu(2, 2)))           // exactly 2 waves/EU -> 256 VGPR budget
__global__ void pqc_kernel(
    const float* __restrict__ x,      // (B, 14)
    const float* __restrict__ theta,  // (252,)
    const float* __restrict__ lam,    // (70,)
    const float* __restrict__ w,      // (1, 2)
    float* __restrict__ out)          // (B, 2)
{
    __shared__ vf2 st[DIM];                    // 128 KiB state, layout L(i)
    __shared__ vf2 G[NLAYERS + 1][NQ][4];      // l=0: RZ*RY*RX; l>=1: (RZ*RY*RX)@RX_enc
    __shared__ float wsum[NTHREADS / 64];

    const int t = threadIdx.x;
    const int b = blockIdx.x;
    char* stb = (char*)st;

    // ---- Build all 84 fused gates (theta layout: 42*l + 3*q + c) ----
    if (t < (NLAYERS + 1) * NQ) {
        const int l = t / NQ, q = t % NQ;
        const float a0 = theta[3 * t + 0];
        const float a1 = theta[3 * t + 1];
        const float a2 = theta[3 * t + 2];
        const float cx = cosf(0.5f * a0), sx = sinf(0.5f * a0);
        const float cy = cosf(0.5f * a1), sy = sinf(0.5f * a1);
        const float cz = cosf(0.5f * a2), sz = sinf(0.5f * a2);
        const c32 m00 = {  cy * cx,  sy * sx };
        const c32 m01 = { -sy * cx, -cy * sx };
        const c32 m10 = {  sy * cx, -cy * sx };
        const c32 m11 = {  cy * cx, -sy * sx };
        c32 u00 = { cz * m00.x + sz * m00.y,  cz * m00.y - sz * m00.x };
        c32 u01 = { cz * m01.x + sz * m01.y,  cz * m01.y - sz * m01.x };
        c32 u10 = { cz * m10.x - sz * m10.y,  cz * m10.y + sz * m10.x };
        c32 u11 = { cz * m11.x - sz * m11.y,  cz * m11.y + sz * m11.x };
        if (l >= 1) {
            const float ang = x[b * NQ + q] * lam[(l - 1) * NQ + q];
            const float c = cosf(0.5f * ang), s = sinf(0.5f * ang);
            const c32 v00 = { u00.x * c + s * u01.y,  u00.y * c - s * u01.x };
            const c32 v01 = { u01.x * c + s * u00.y,  u01.y * c - s * u00.x };
            const c32 v10 = { u10.x * c + s * u11.y,  u10.y * c - s * u11.x };
            const c32 v11 = { u11.x * c + s * u10.y,  u11.y * c - s * u10.x };
            u00 = v00; u01 = v01; u10 = v10; u11 = v11;
        }
        G[l][q][0] = vf2{ u00.x, u00.y };
        G[l][q][1] = vf2{ u01.x, u01.y };
        G[l][q][2] = vf2{ u10.x, u10.y };
        G[l][q][3] = vf2{ u11.x, u11.y };
    }
    __syncthreads();

    // ---- Per-thread bases (byte offsets) and ring-sign masks ----
    const int base1 = lswz(t) << 3;                                   // P1: i=(j<<9)|t
    const int base2 = lswz(((t & 0x1F0) << 5) | (t & 15)) << 3;       // P2
    const int base3 = lswz(t << 4) << 3;                              // P3 / init
    const unsigned Pp  = (unsigned)(__popc(t & (t >> 1) & 0xFF) & 1); // pairs (8,7)..(1,0) of t
    const unsigned t8 = (t >> 8) & 1u, tb0 = t & 1u;
    const unsigned M00 =  Pp              << 31;
    const unsigned M10 = (Pp ^ t8)        << 31;
    const unsigned M01 = (Pp ^ tb0)       << 31;
    const unsigned M11 = (Pp ^ t8 ^ tb0)  << 31;

    // ---- Layer 0 analytically: |0..0> through U0 is a tensor product ----
    // i = (v<<13)|(t<<4)|j : qubit0<-v, qubits1..9<-t bits 8..0, qubits10..13<-j.
    {
        c32 pref = { G[0][1][((t >> 8) & 1) ? 2 : 0].x, G[0][1][((t >> 8) & 1) ? 2 : 0].y };
        #pragma unroll
        for (int qq = 2; qq <= 9; ++qq) {
            const vf2 g = G[0][qq][((t >> (9 - qq)) & 1) ? 2 : 0];
            pref = cmul(pref, c32{ g.x, g.y });
        }
        const c32 g00a = { G[0][0][0].x, G[0][0][0].y };
        const c32 g00b = { G[0][0][2].x, G[0][0][2].y };
        const c32 pv[2] = { cmul(pref, g00a), cmul(pref, g00b) };
        c32 p01[4], p23[4];
        #pragma unroll
        for (int k = 0; k < 4; ++k) {
            const vf2 ga = G[0][10][(k >> 1) ? 2 : 0], gb = G[0][11][(k & 1) ? 2 : 0];
            const vf2 gc = G[0][12][(k >> 1) ? 2 : 0], gd = G[0][13][(k & 1) ? 2 : 0];
            p01[k] = cmul(c32{ ga.x, ga.y }, c32{ gb.x, gb.y });
            p23[k] = cmul(c32{ gc.x, gc.y }, c32{ gd.x, gd.y });
        }
        #pragma unroll
        for (int v = 0; v < 2; ++v)
            #pragma unroll
            for (int j = 0; j < 16; ++j) {
                const c32 av = cmul(cmul(pv[v], p01[j >> 2]), p23[j & 3]);
                *(vf2*)(stb + (base3 ^ (lswz(v << 13) << 3) ^ (j << 3))) = vf2{ av.x, av.y };
            }
    }
    __syncthreads();

    float se = 0.f, so = 0.f;

    #pragma unroll 1
    for (int l = 1; l <= NLAYERS; ++l) {
        // ---- P1: bits 13..9 (q0..q4), ring sign fused on load ----
        {
            vf2 ga[5][4];
            #pragma unroll
            for (int q = 0; q < 5; ++q) {
                ga[q][0] = G[l][q][0]; ga[q][1] = G[l][q][1];
                ga[q][2] = G[l][q][2]; ga[q][3] = G[l][q][3];
            }
            vf2 a[32];
            #pragma unroll
            for (int j = 0; j < 32; ++j) {
                const vf2 v = *(const vf2*)(stb + (base1 ^ (lswz(j << 9) << 3)));
                const unsigned mj = ((j & 1) ? (((j >> 4) & 1) ? M11 : M10)
                                             : (((j >> 4) & 1) ? M01 : M00))
                                    ^ (sjc(j) << 31);
                a[j] = vf2{ __uint_as_float(__float_as_uint(v.x) ^ mj),
                            __uint_as_float(__float_as_uint(v.y) ^ mj) };
            }
            APPLY32(4, ga[0]); APPLY32(3, ga[1]); APPLY32(2, ga[2]);
            APPLY32(1, ga[3]); APPLY32(0, ga[4]);
            #pragma unroll
            for (int j = 0; j < 32; ++j)
                *(vf2*)(stb + (base1 ^ (lswz(j << 9) << 3))) = a[j];
        }
        __syncthreads();

        // ---- P2: bits 8..4 (q5..q9) ----
        {
            vf2 ga[5][4];
            #pragma unroll
            for (int q = 0; q < 5; ++q) {
                ga[q][0] = G[l][5 + q][0]; ga[q][1] = G[l][5 + q][1];
                ga[q][2] = G[l][5 + q][2]; ga[q][3] = G[l][5 + q][3];
            }
            vf2 a[32];
            #pragma unroll
            for (int j = 0; j < 32; ++j)
                a[j] = *(const vf2*)(stb + (base2 ^ (lswz(j << 4) << 3)));
            APPLY32(4, ga[0]); APPLY32(3, ga[1]); APPLY32(2, ga[2]);
            APPLY32(1, ga[3]); APPLY32(0, ga[4]);
            #pragma unroll
            for (int j = 0; j < 32; ++j)
                *(vf2*)(stb + (base2 ^ (lswz(j << 4) << 3))) = a[j];
        }
        __syncthreads();

        // ---- P3: bits 3..0 (q10..q13); last layer: fold in <Z^14> ----
        {
            vf2 gb[4][4];
            #pragma unroll
            for (int q = 0; q < 4; ++q) {
                gb[q][0] = G[l][10 + q][0]; gb[q][1] = G[l][10 + q][1];
                gb[q][2] = G[l][10 + q][2]; gb[q][3] = G[l][10 + q][3];
            }
            #pragma unroll
            for (int v = 0; v < 2; ++v) {
                vf2 aa[16];
                #pragma unroll
                for (int j = 0; j < 16; ++j)
                    aa[j] = *(const vf2*)(stb + (base3 ^ (lswz(v << 13) << 3) ^ (j << 3)));
                APPLY16(3, gb[0]); APPLY16(2, gb[1]);
                APPLY16(1, gb[2]); APPLY16(0, gb[3]);
                if (l < NLAYERS) {
                    #pragma unroll
                    for (int j = 0; j < 16; ++j)
                        *(vf2*)(stb + (base3 ^ (lswz(v << 13) << 3) ^ (j << 3))) = aa[j];
                } else {
                    #pragma unroll
                    for (int j = 0; j < 16; ++j) {
                        const float d = fmaf(aa[j].x, aa[j].x, aa[j].y * aa[j].y);
                        if (((v ^ __popc(j)) & 1) == 0) se += d; else so += d;
                    }
                }
            }
        }
        if (l < NLAYERS) __syncthreads();
    }

    // ---- Reduce + softmax ----
    float local = (__popc(t) & 1) ? (so - se) : (se - so);
    #pragma unroll
    for (int off = 32; off > 0; off >>= 1)
        local += __shfl_down(local, off, 64);
    if ((t & 63) == 0) wsum[t >> 6] = local;
    __syncthreads();
    if (t == 0) {
        float v = 0.0f;
        #pragma unroll
        for (int i = 0; i < NTHREADS / 64; ++i) v += wsum[i];
        const float BETA = 1.0f;
        const float l0 = v * w[0] * BETA, l1 = v * w[1] * BETA;
        const float m  = fmaxf(l0, l1);
        const float e0 = __expf(l0 - m), e1 = __expf(l1 - m);
        const float inv = 1.0f / (e0 + e1);
        out[2 * b + 0] = e0 * inv;
        out[2 * b + 1] = e1 * inv;
    }
}

extern "C" void kernel_launch(void* const* d_in, const int* in_sizes, int n_in,
                              void* d_out, int out_size, void* d_ws, size_t ws_size,
                              hipStream_t stream) {
    const float* x     = (const float*)d_in[0];
    const float* theta = (const float*)d_in[1];
    const float* lam   = (const float*)d_in[2];
    const float* w     = (const float*)d_in[3];
    float* out = (float*)d_out;
    const int batch = in_sizes[0] / NQ;   // 2048
    pqc_kernel<<<batch, NTHREADS, 0, stream>>>(x, theta, lam, w, out);
}

// Round 8
// 376.147 us; speedup vs baseline: 13.8417x; 1.0526x over previous
//
#include <hip/hip_runtime.h>
#include <math.h>

#define NQ        14
#define DIM       16384          // 2^14
#define NLAYERS   5
#define NTHREADS  512            // 32 amps/thread

typedef float vf2 __attribute__((ext_vector_type(2)));
struct c32 { float x, y; };

// GF(2)-LINEAR layout: L(i) = i ^ sigma(i), sigma image in bits 3:0, inputs bits>=4.
// Linear => pass addresses = thread_base ^ compile-time const. Conflict-free for
// A/B/C pass patterns (hand-verified, r6/r7).
__host__ __device__ constexpr int lswz(int i) {
    return i ^ ((i >> 4) & 15) ^ ((i >> 8) & 15) ^ ((i >> 12) & 3);
}
// Adjacent-pair parity of 5-bit j (A-window internal ring pairs).
__host__ __device__ constexpr unsigned sjc(int j) {
    return (((j >> 4) & (j >> 3)) ^ ((j >> 3) & (j >> 2)) ^
            ((j >> 2) & (j >> 1)) ^ ((j >> 1) & j)) & 1u;
}
// Adjacent-pair parity of 4-bit j (C-window internal ring pairs).
__host__ __device__ constexpr unsigned pjc(int j) {
    return (((j >> 3) & (j >> 2)) ^ ((j >> 2) & (j >> 1)) ^ ((j >> 1) & j)) & 1u;
}

__device__ __forceinline__ c32 cmul(c32 a, c32 b) {
    return { a.x * b.x - a.y * b.y, a.x * b.y + a.y * b.x };
}
__device__ __forceinline__ vf2 sxor(vf2 v, unsigned m) {
    return vf2{ __uint_as_float(__float_as_uint(v.x) ^ m),
                __uint_as_float(__float_as_uint(v.y) ^ m) };
}

// Complex butterfly in 8 VOP3P instrs (r7, verified). Coefficient broadcast via
// op_sel; perp(A)=(-A.y,A.x) via op_sel:[1],op_sel_hi:[0],neg_lo:[1].
__device__ __forceinline__ void bf(vf2 g0, vf2 g1, vf2 g2, vf2 g3,
                                   vf2& A0, vf2& A1) {
    vf2 b0, b1;
    asm("v_pk_mul_f32 %0, %3, %7 op_sel:[1,1] op_sel_hi:[1,0] neg_lo:[0,1] neg_hi:[0,0]\n\t"
        "v_pk_mul_f32 %1, %5, %7 op_sel:[1,1] op_sel_hi:[1,0] neg_lo:[0,1] neg_hi:[0,0]\n\t"
        "v_pk_fma_f32 %0, %3, %7, %0 op_sel:[0,0,0] op_sel_hi:[0,1,1]\n\t"
        "v_pk_fma_f32 %1, %5, %7, %1 op_sel:[0,0,0] op_sel_hi:[0,1,1]\n\t"
        "v_pk_fma_f32 %0, %2, %6, %0 op_sel:[1,1,0] op_sel_hi:[1,0,1] neg_lo:[0,1,0] neg_hi:[0,0,0]\n\t"
        "v_pk_fma_f32 %1, %4, %6, %1 op_sel:[1,1,0] op_sel_hi:[1,0,1] neg_lo:[0,1,0] neg_hi:[0,0,0]\n\t"
        "v_pk_fma_f32 %0, %2, %6, %0 op_sel:[0,0,0] op_sel_hi:[0,1,1]\n\t"
        "v_pk_fma_f32 %1, %4, %6, %1 op_sel:[0,0,0] op_sel_hi:[0,1,1]"
        : "=&v"(b0), "=&v"(b1)
        : "v"(g0), "v"(g1), "v"(g2), "v"(g3), "v"(A0), "v"(A1));
    A0 = b0; A1 = b1;
}

#define APPLY32(K, GG) { _Pragma("unroll") \
    for (int mm = 0; mm < 16; ++mm) { \
        const int r0 = ((mm >> (K)) << ((K) + 1)) | (mm & ((1 << (K)) - 1)); \
        bf((GG)[0], (GG)[1], (GG)[2], (GG)[3], a[r0], a[r0 | (1 << (K))]); } }
#define APPLY16(K, GG) { _Pragma("unroll") \
    for (int mm = 0; mm < 8; ++mm) { \
        const int r0 = ((mm >> (K)) << ((K) + 1)) | (mm & ((1 << (K)) - 1)); \
        bf((GG)[0], (GG)[1], (GG)[2], (GG)[3], aa[r0], aa[r0 | (1 << (K))]); } }

#define LOADG5(gg, Gl, q0) { _Pragma("unroll") \
    for (int q = 0; q < 5; ++q) { \
        gg[q][0] = (Gl)[(q0) + q][0]; gg[q][1] = (Gl)[(q0) + q][1]; \
        gg[q][2] = (Gl)[(q0) + q][2]; gg[q][3] = (Gl)[(q0) + q][3]; } }
#define LOADG4(gg, Gl, q0) { _Pragma("unroll") \
    for (int q = 0; q < 4; ++q) { \
        gg[q][0] = (Gl)[(q0) + q][0]; gg[q][1] = (Gl)[(q0) + q][1]; \
        gg[q][2] = (Gl)[(q0) + q][2]; gg[q][3] = (Gl)[(q0) + q][3]; } }

// Ring-sign mask for A-window amp j (i = (j<<9)|t):  sign = sjc(j) ^ j0*t8 ^ P_t ^ t0*j4
#define AMASK(j) ((((j) & 1) ? (((j) & 16) ? M11 : M10) : (((j) & 16) ? M01 : M00)) \
                  ^ (sjc(j) << 31))
// Ring-sign mask for C-window amp (v,j) (i = (v<<13)|(t<<4)|j):
//   sign = P_t ^ v*t8 ^ t0*j3 ^ pjc(j) ^ j0*v
#define CMASK(v, j) ((((v)) ? (((j) & 8) ? C11 : C10) : (((j) & 8) ? C01 : C00)) \
                     ^ (((pjc(j) ^ ((j) & (v) & 1)) & 1u) << 31))

// ---- B pass: bits 8..4, gates q5..9 of layer Gl ----
__device__ __forceinline__ void passB(char* stb, const vf2 (*Gl)[4], int base2) {
    vf2 ga[5][4];
    LOADG5(ga, Gl, 5);
    vf2 a[32];
    #pragma unroll
    for (int j = 0; j < 32; ++j)
        a[j] = *(const vf2*)(stb + (base2 ^ (lswz(j << 4) << 3)));
    APPLY32(4, ga[0]); APPLY32(3, ga[1]); APPLY32(2, ga[2]);
    APPLY32(1, ga[3]); APPLY32(0, ga[4]);
    #pragma unroll
    for (int j = 0; j < 32; ++j)
        *(vf2*)(stb + (base2 ^ (lswz(j << 4) << 3))) = a[j];
}

// ---- Fused A pass: gates q0..4 of la, ring sign, gates q0..4 of lb ----
__device__ __forceinline__ void passAA(char* stb, const vf2 (*Gla)[4], const vf2 (*Glb)[4],
                                       int base1, unsigned M00, unsigned M01,
                                       unsigned M10, unsigned M11) {
    vf2 ga[5][4];
    LOADG5(ga, Gla, 0);
    vf2 a[32];
    #pragma unroll
    for (int j = 0; j < 32; ++j)
        a[j] = *(const vf2*)(stb + (base1 ^ (lswz(j << 9) << 3)));
    APPLY32(4, ga[0]); APPLY32(3, ga[1]); APPLY32(2, ga[2]);
    APPLY32(1, ga[3]); APPLY32(0, ga[4]);
    vf2 gb[5][4];
    LOADG5(gb, Glb, 0);
    #pragma unroll
    for (int j = 0; j < 32; ++j) a[j] = sxor(a[j], AMASK(j));
    APPLY32(4, gb[0]); APPLY32(3, gb[1]); APPLY32(2, gb[2]);
    APPLY32(1, gb[3]); APPLY32(0, gb[4]);
    #pragma unroll
    for (int j = 0; j < 32; ++j)
        *(vf2*)(stb + (base1 ^ (lswz(j << 9) << 3))) = a[j];
}

// ---- Fused C pass: gates q10..13 of la, ring sign, gates q10..13 of lb ----
__device__ __forceinline__ void passCC(char* stb, const vf2 (*Gla)[4], const vf2 (*Glb)[4],
                                       int base3, unsigned C00, unsigned C01,
                                       unsigned C10, unsigned C11) {
    vf2 ga[4][4], gb[4][4];
    LOADG4(ga, Gla, 10);
    LOADG4(gb, Glb, 10);
    #pragma unroll
    for (int v = 0; v < 2; ++v) {
        const int bb = base3 ^ (lswz(v << 13) << 3);
        vf2 aa[16];
        #pragma unroll
        for (int j = 0; j < 16; ++j)
            aa[j] = *(const vf2*)(stb + (bb ^ (j << 3)));
        APPLY16(3, ga[0]); APPLY16(2, ga[1]); APPLY16(1, ga[2]); APPLY16(0, ga[3]);
        #pragma unroll
        for (int j = 0; j < 16; ++j) aa[j] = sxor(aa[j], CMASK(v, j));
        APPLY16(3, gb[0]); APPLY16(2, gb[1]); APPLY16(1, gb[2]); APPLY16(0, gb[3]);
        #pragma unroll
        for (int j = 0; j < 16; ++j)
            *(vf2*)(stb + (bb ^ (j << 3))) = aa[j];
    }
}

// ---- Last C pass: gates q10..13 of l, accumulate <Z^14> ----
__device__ __forceinline__ void passCLast(char* stb, const vf2 (*Gl)[4], int base3,
                                          float& se, float& so) {
    vf2 ga[4][4];
    LOADG4(ga, Gl, 10);
    #pragma unroll
    for (int v = 0; v < 2; ++v) {
        const int bb = base3 ^ (lswz(v << 13) << 3);
        vf2 aa[16];
        #pragma unroll
        for (int j = 0; j < 16; ++j)
            aa[j] = *(const vf2*)(stb + (bb ^ (j << 3)));
        APPLY16(3, ga[0]); APPLY16(2, ga[1]); APPLY16(1, ga[2]); APPLY16(0, ga[3]);
        #pragma unroll
        for (int j = 0; j < 16; ++j) {
            const float d = fmaf(aa[j].x, aa[j].x, aa[j].y * aa[j].y);
            if (((v ^ __popc(j)) & 1) == 0) se += d; else so += d;
        }
    }
}

__attribute__((amdgpu_flat_work_group_size(NTHREADS, NTHREADS),
               amdgpu_waves_per_eu(2, 2)))           // exactly 2 waves/EU -> 256 VGPR budget
__global__ void pqc_kernel(
    const float* __restrict__ x,      // (B, 14)
    const float* __restrict__ theta,  // (252,)
    const float* __restrict__ lam,    // (70,)
    const float* __restrict__ w,      // (1, 2)
    float* __restrict__ out)          // (B, 2)
{
    __shared__ vf2 st[DIM];                    // 128 KiB state, layout L(i)
    __shared__ vf2 G[NLAYERS + 1][NQ][4];      // l=0: RZ*RY*RX; l>=1: (RZ*RY*RX)@RX_enc
    __shared__ float wsum[NTHREADS / 64];

    const int t = threadIdx.x;
    const int b = blockIdx.x;
    char* stb = (char*)st;

    // ---- Build all 84 fused gates (theta layout: 42*l + 3*q + c) ----
    if (t < (NLAYERS + 1) * NQ) {
        const int l = t / NQ, q = t % NQ;
        const float a0 = theta[3 * t + 0];
        const float a1 = theta[3 * t + 1];
        const float a2 = theta[3 * t + 2];
        const float cx = cosf(0.5f * a0), sx = sinf(0.5f * a0);
        const float cy = cosf(0.5f * a1), sy = sinf(0.5f * a1);
        const float cz = cosf(0.5f * a2), sz = sinf(0.5f * a2);
        const c32 m00 = {  cy * cx,  sy * sx };
        const c32 m01 = { -sy * cx, -cy * sx };
        const c32 m10 = {  sy * cx, -cy * sx };
        const c32 m11 = {  cy * cx, -sy * sx };
        c32 u00 = { cz * m00.x + sz * m00.y,  cz * m00.y - sz * m00.x };
        c32 u01 = { cz * m01.x + sz * m01.y,  cz * m01.y - sz * m01.x };
        c32 u10 = { cz * m10.x - sz * m10.y,  cz * m10.y + sz * m10.x };
        c32 u11 = { cz * m11.x - sz * m11.y,  cz * m11.y + sz * m11.x };
        if (l >= 1) {
            const float ang = x[b * NQ + q] * lam[(l - 1) * NQ + q];
            const float c = cosf(0.5f * ang), s = sinf(0.5f * ang);
            const c32 v00 = { u00.x * c + s * u01.y,  u00.y * c - s * u01.x };
            const c32 v01 = { u01.x * c + s * u00.y,  u01.y * c - s * u00.x };
            const c32 v10 = { u10.x * c + s * u11.y,  u10.y * c - s * u11.x };
            const c32 v11 = { u11.x * c + s * u10.y,  u11.y * c - s * u10.x };
            u00 = v00; u01 = v01; u10 = v10; u11 = v11;
        }
        G[l][q][0] = vf2{ u00.x, u00.y };
        G[l][q][1] = vf2{ u01.x, u01.y };
        G[l][q][2] = vf2{ u10.x, u10.y };
        G[l][q][3] = vf2{ u11.x, u11.y };
    }
    __syncthreads();

    // ---- Per-thread bases (byte offsets) ----
    const int base1 = lswz(t) << 3;                                   // A: i=(j<<9)|t
    const int base2 = lswz(((t & 0x1F0) << 5) | (t & 15)) << 3;       // B
    const int base3 = lswz(t << 4) << 3;                              // C: i=(v<<13)|(t<<4)|j
    // ---- Ring-sign per-thread words ----
    const unsigned Pp  = (unsigned)(__popc(t & (t >> 1) & 0xFF) & 1); // t adjacent-pair parity
    const unsigned t8 = (t >> 8) & 1u, tb0 = t & 1u;
    // A-window: j0 selects t8, j4 selects t0
    const unsigned M00 =  Pp              << 31;
    const unsigned M10 = (Pp ^ t8)        << 31;
    const unsigned M01 = (Pp ^ tb0)       << 31;
    const unsigned M11 = (Pp ^ t8 ^ tb0)  << 31;
    // C-window: v selects t8, j3 selects t0
    const unsigned C00 =  Pp              << 31;
    const unsigned C01 = (Pp ^ tb0)       << 31;
    const unsigned C10 = (Pp ^ t8)        << 31;
    const unsigned C11 = (Pp ^ t8 ^ tb0)  << 31;

    // ================= Pass 1: analytic U0 state + ring sign + W1 q0..4 =========
    // A-window: i = (j<<9)|t. qubits 0..4 <- j bits 4..0; qubits 5..13 <- t bits 8..0.
    {
        vf2 ga[5][4];
        LOADG5(ga, G[1], 0);
        c32 pref = { G[0][5][((t >> 8) & 1) ? 2 : 0].x, G[0][5][((t >> 8) & 1) ? 2 : 0].y };
        #pragma unroll
        for (int qq = 6; qq <= 13; ++qq) {
            const vf2 g = G[0][qq][((t >> (13 - qq)) & 1) ? 2 : 0];
            pref = cmul(pref, c32{ g.x, g.y });
        }
        c32 pp01[4], p234[8];
        #pragma unroll
        for (int k = 0; k < 4; ++k) {
            const vf2 g0 = G[0][0][(k >> 1) ? 2 : 0], g1 = G[0][1][(k & 1) ? 2 : 0];
            pp01[k] = cmul(pref, cmul(c32{ g0.x, g0.y }, c32{ g1.x, g1.y }));
        }
        #pragma unroll
        for (int m = 0; m < 8; ++m) {
            const vf2 g2 = G[0][2][(m >> 2) ? 2 : 0];
            const vf2 g3 = G[0][3][((m >> 1) & 1) ? 2 : 0];
            const vf2 g4 = G[0][4][(m & 1) ? 2 : 0];
            p234[m] = cmul(cmul(c32{ g2.x, g2.y }, c32{ g3.x, g3.y }), c32{ g4.x, g4.y });
        }
        vf2 a[32];
        #pragma unroll
        for (int j = 0; j < 32; ++j) {
            const c32 av = cmul(pp01[j >> 3], p234[j & 7]);
            a[j] = sxor(vf2{ av.x, av.y }, AMASK(j));
        }
        APPLY32(4, ga[0]); APPLY32(3, ga[1]); APPLY32(2, ga[2]);
        APPLY32(1, ga[3]); APPLY32(0, ga[4]);
        #pragma unroll
        for (int j = 0; j < 32; ++j)
            *(vf2*)(stb + (base1 ^ (lswz(j << 9) << 3))) = a[j];
    }
    __syncthreads();

    // ================= Fused 11-pass schedule =================
    passB(stb, G[1], base2);                               __syncthreads();
    passCC(stb, G[1], G[2], base3, C00, C01, C10, C11);    __syncthreads();
    passB(stb, G[2], base2);                               __syncthreads();
    passAA(stb, G[2], G[3], base1, M00, M01, M10, M11);    __syncthreads();
    passB(stb, G[3], base2);                               __syncthreads();
    passCC(stb, G[3], G[4], base3, C00, C01, C10, C11);    __syncthreads();
    passB(stb, G[4], base2);                               __syncthreads();
    passAA(stb, G[4], G[5], base1, M00, M01, M10, M11);    __syncthreads();
    passB(stb, G[5], base2);                               __syncthreads();
    float se = 0.f, so = 0.f;
    passCLast(stb, G[5], base3, se, so);

    // ---- Reduce + softmax ----
    float local = (__popc(t) & 1) ? (so - se) : (se - so);
    #pragma unroll
    for (int off = 32; off > 0; off >>= 1)
        local += __shfl_down(local, off, 64);
    if ((t & 63) == 0) wsum[t >> 6] = local;
    __syncthreads();
    if (t == 0) {
        float v = 0.0f;
        #pragma unroll
        for (int i = 0; i < NTHREADS / 64; ++i) v += wsum[i];
        const float BETA = 1.0f;
        const float l0 = v * w[0] * BETA, l1 = v * w[1] * BETA;
        const float m  = fmaxf(l0, l1);
        const float e0 = __expf(l0 - m), e1 = __expf(l1 - m);
        const float inv = 1.0f / (e0 + e1);
        out[2 * b + 0] = e0 * inv;
        out[2 * b + 1] = e1 * inv;
    }
}

extern "C" void kernel_launch(void* const* d_in, const int* in_sizes, int n_in,
                              void* d_out, int out_size, void* d_ws, size_t ws_size,
                              hipStream_t stream) {
    const float* x     = (const float*)d_in[0];
    const float* theta = (const float*)d_in[1];
    const float* lam   = (const float*)d_in[2];
    const float* w     = (const float*)d_in[3];
    float* out = (float*)d_out;
    const int batch = in_sizes[0] / NQ;   // 2048
    pqc_kernel<<<batch, NTHREADS, 0, stream>>>(x, theta, lam, w, out);
}